// Round 5
// baseline (1331.320 us; speedup 1.0000x reference)
//
#include <hip/hip_runtime.h>
#include <hip/hip_bf16.h>

// TemporalEMA: out = ALPHA * bilinear_warp(prev, mv) + (1-ALPHA) * cur
// R5: fixed-window LDS staging v2. R3's killers fixed:
//   - static geometry: tile 64x24, halo +-16 -> 58x99 floats = 23KB LDS -> 6 blocks/CU
//   - coalesced dword staging, no dynamic bbox reduction
//   - per-pixel `inside` predicate, rare (~3e-5) global-gather fallback keeps exactness
//   - border clamp folded into weights (x0=min(floor,W-2), wx absorbs; verified R4)
// Goal: convert ~650K random cache-line ops/CU (the measured wall) into
// coalesced L2 streams + LDS random reads (b32 pairs, ~2-way conflicts = free).

#define ALPHA 0.85f

constexpr int Bc = 4;
constexpr int Cc = 16;
constexpr int Hc = 1080;
constexpr int Wc = 1920;

constexpr int TW = 64;
constexpr int TH = 24;                 // 1080 = 45*24
constexpr int MARG = 16;
constexpr int PPT = TW * TH / 256;     // 6 pixels/thread
constexpr int NX = Wc / TW;            // 30
constexpr int NY = Hc / TH;            // 45
constexpr int NBLK = Bc * NY * NX;     // 5400
constexpr int NXCD = 8;
constexpr int CHUNK = NBLK / NXCD;     // 675 (divisible -> bijective swizzle)

constexpr int WW = TW + 2 * MARG + 2;  // 98 max window width
constexpr int WH = TH + 2 * MARG + 2;  // 58 max window height
constexpr int STRIDE = WW + 1;         // 99 (odd -> bank spread)

__global__ __launch_bounds__(256, 6) void TemporalEMA_73194832658797_kernel(
    const float* __restrict__ cur,
    const float* __restrict__ prev,
    const float* __restrict__ mv,
    float* __restrict__ out)
{
    __shared__ float tile[WH * STRIDE];   // 5742 floats = 22968 B

    const int bid  = blockIdx.x;
    const int work = (bid % NXCD) * CHUNK + bid / NXCD;  // chunked XCD swizzle

    const int tx  = work % NX;
    const int rem = work / NX;
    const int ty  = rem % NY;
    const int b   = rem / NY;

    const int lw = threadIdx.x & 63;
    const int lh = threadIdx.x >> 6;       // 0..3
    const int w  = tx * TW + lw;
    const int h0 = ty * TH;

    // staging window (block-uniform)
    const int wy0 = max(0, h0 - MARG);
    const int wy1 = min(Hc - 1, h0 + TH - 1 + MARG + 1);
    const int wx0 = max(0, tx * TW - MARG);
    const int wx1 = min(Wc - 1, tx * TW + TW - 1 + MARG + 1);
    const int wh = wy1 - wy0 + 1;          // <= 58
    const int ww = wx1 - wx0 + 1;          // <= 98 (>= 81)

    const size_t plane  = (size_t)Hc * Wc;
    const size_t base_b = (size_t)b * Cc * plane;
    const float sxk = (float)(Wc - 1) / (float)Wc;
    const float syk = (float)(Hc - 1) / (float)Hc;

    // ---- per-pixel setup ----
    int   off00[PPT];   // LDS offset of v00 (valid only if inside)
    int   pk[PPT];      // packed (y0<<16)|x0 for fallback
    int   pixv[PPT];    // global pixel offset within a plane
    float wxv[PPT], wyv[PPT];
    unsigned insmask = 0;

    #pragma unroll
    for (int i = 0; i < PPT; ++i) {
        const int h = h0 + lh + 4 * i;
        const int pix = h * Wc + w;
        pixv[i] = pix;
        const float mvx = __builtin_nontemporal_load(&mv[((size_t)b * 2 + 0) * plane + pix]);
        const float mvy = __builtin_nontemporal_load(&mv[((size_t)b * 2 + 1) * plane + pix]);
        float px = fminf(fmaxf((float)w - mvx * sxk, 0.0f), (float)(Wc - 1));
        float py = fminf(fmaxf((float)h - mvy * syk, 0.0f), (float)(Hc - 1));
        const int x0 = min((int)floorf(px), Wc - 2);
        const int y0 = min((int)floorf(py), Hc - 2);
        wxv[i] = px - (float)x0;           // weights absorb border clamp
        wyv[i] = py - (float)y0;
        pk[i] = (y0 << 16) | x0;
        off00[i] = (y0 - wy0) * STRIDE + (x0 - wx0);
        const bool ins = (x0 >= wx0) & (x0 + 1 <= wx1) & (y0 >= wy0) & (y0 + 1 <= wy1);
        insmask |= (unsigned)ins << i;
    }

    // ---- channel loop: stage -> compute ----
    for (int c = 0; c < Cc; ++c) {
        __syncthreads();                   // tile free before overwrite
        const float* __restrict__ src = prev + base_b + (size_t)c * plane;
        for (int r = lh; r < wh; r += 4) {
            const float* row = src + (size_t)(wy0 + r) * Wc + wx0;
            float* dst = &tile[r * STRIDE];
            dst[lw] = row[lw];                              // ww >= 81 > 63: always
            if (lw + 64 < ww) dst[lw + 64] = row[lw + 64];
        }
        __syncthreads();

        const size_t cb = base_b + (size_t)c * plane;
        #pragma unroll
        for (int i = 0; i < PPT; ++i) {
            float v00, v01, v10, v11;
            if (insmask & (1u << i)) {
                const int o = off00[i];
                v00 = tile[o];
                v01 = tile[o + 1];
                v10 = tile[o + STRIDE];
                v11 = tile[o + STRIDE + 1];
            } else {                        // rare (~3e-5): direct global gather
                const int x0 = pk[i] & 0xffff, y0 = pk[i] >> 16;
                const float* g = prev + cb + (size_t)y0 * Wc + x0;
                v00 = g[0]; v01 = g[1]; v10 = g[Wc]; v11 = g[Wc + 1];
            }
            const float wx = wxv[i], wy = wyv[i];
            const float warped = (v00 * (1.0f - wx) + v01 * wx) * (1.0f - wy)
                               + (v10 * (1.0f - wx) + v11 * wx) * wy;
            const float cu = __builtin_nontemporal_load(&cur[cb + pixv[i]]);
            __builtin_nontemporal_store(ALPHA * warped + (1.0f - ALPHA) * cu,
                                        &out[cb + pixv[i]]);
        }
    }
}

extern "C" void kernel_launch(void* const* d_in, const int* in_sizes, int n_in,
                              void* d_out, int out_size, void* d_ws, size_t ws_size,
                              hipStream_t stream) {
    const float* cur  = (const float*)d_in[0];
    const float* prev = (const float*)d_in[1];
    const float* mv   = (const float*)d_in[2];
    float* out = (float*)d_out;

    TemporalEMA_73194832658797_kernel<<<NBLK, 256, 0, stream>>>(cur, prev, mv, out);
}

// Round 6
// 786.984 us; speedup vs baseline: 1.6917x; 1.6917x over previous
//
#include <hip/hip_runtime.h>
#include <hip/hip_bf16.h>

// TemporalEMA: out = ALPHA * bilinear_warp(prev, mv) + (1-ALPHA) * cur
// R6: direct gather (R4 structure) + thread-coarsening in y: each wave owns
//     64w x 9h; loop CHANNEL-OUTER, ROW-INNER so 9 consecutive rows of one
//     channel gather back-to-back -> their footprints overlap ~96% -> L1 hits
//     for rows 1..8, cutting L2->L1 line-refill (~14 GB in R4, the measured
//     wall) by ~3x. No LDS, no barriers (staging structurally loses: R3/R5).
//     Border clamp folded into weights (verified bit-exact R4/R5).

#define ALPHA 0.85f

constexpr int Bc = 4;
constexpr int Cc = 16;
constexpr int Hc = 1080;
constexpr int Wc = 1920;

constexpr int TW   = 64;             // lanes span 64 px in x
constexpr int PPTY = 9;              // rows per thread
constexpr int TH   = 4 * PPTY;       // 36 rows per block (4 waves)
constexpr int NX = Wc / TW;          // 30
constexpr int NY = Hc / TH;          // 30
constexpr int NBLK = Bc * NY * NX;   // 3600
constexpr int NXCD = 8;
constexpr int CHUNK = NBLK / NXCD;   // 450 (divisible -> bijective swizzle)

typedef float f2 __attribute__((ext_vector_type(2)));

__global__ __launch_bounds__(256) void TemporalEMA_73194832658797_kernel(
    const float* __restrict__ cur,
    const float* __restrict__ prev,
    const float* __restrict__ mv,
    float* __restrict__ out)
{
    // chunked XCD swizzle: contiguous work slab per XCD -> halo reuse in its L2
    const int bid  = blockIdx.x;
    const int work = (bid % NXCD) * CHUNK + bid / NXCD;

    const int tx  = work % NX;
    const int rem = work / NX;
    const int ty  = rem % NY;
    const int b   = rem / NY;

    const int lw = threadIdx.x & 63;
    const int lh = threadIdx.x >> 6;              // wave id 0..3
    const int w  = tx * TW + lw;
    const int h0 = ty * TH + lh * PPTY;           // 9 consecutive rows per wave

    const size_t plane  = (size_t)Hc * Wc;
    const size_t base_b = (size_t)b * Cc * plane;
    const float sxk = (float)(Wc - 1) / (float)Wc;
    const float syk = (float)(Hc - 1) / (float)Hc;

    // ---- per-row sample setup (reused across all 16 channels) ----
    int   pixv[PPTY];      // pixel offset within a plane
    int   o0v[PPTY];       // plane offset of (y0, x0) pair base
    float wxv[PPTY], wyv[PPTY];

    #pragma unroll
    for (int r = 0; r < PPTY; ++r) {
        const int h   = h0 + r;
        const int pix = h * Wc + w;
        pixv[r] = pix;
        const float mvx = __builtin_nontemporal_load(&mv[((size_t)b * 2 + 0) * plane + pix]);
        const float mvy = __builtin_nontemporal_load(&mv[((size_t)b * 2 + 1) * plane + pix]);
        float px = fminf(fmaxf((float)w - mvx * sxk, 0.0f), (float)(Wc - 1));
        float py = fminf(fmaxf((float)h - mvy * syk, 0.0f), (float)(Hc - 1));
        const int x0 = min((int)floorf(px), Wc - 2);   // weights absorb border
        const int y0 = min((int)floorf(py), Hc - 2);
        wxv[r] = px - (float)x0;
        wyv[r] = py - (float)y0;
        o0v[r] = y0 * Wc + x0;
    }

    // ---- channel-outer, row-inner: consecutive rows of one plane gather
    //      back-to-back -> L1 temporal reuse of overlapping lines ----
    #pragma unroll 1
    for (int c = 0; c < Cc; ++c) {
        const float* __restrict__ pc = prev + base_b + (size_t)c * plane;
        const float* __restrict__ cc = cur  + base_b + (size_t)c * plane;
        float* __restrict__       oc = out  + base_b + (size_t)c * plane;

        f2 p0[PPTY], p1[PPTY];
        float cu[PPTY];
        #pragma unroll
        for (int r = 0; r < PPTY; ++r) {
            p0[r] = *(const f2*)(pc + o0v[r]);        // (v00, v01)
            p1[r] = *(const f2*)(pc + o0v[r] + Wc);   // (v10, v11)
            cu[r] = __builtin_nontemporal_load(&cc[pixv[r]]);
        }
        #pragma unroll
        for (int r = 0; r < PPTY; ++r) {
            const float wx = wxv[r], wy = wyv[r];
            const float warped = (p0[r].x * (1.0f - wx) + p0[r].y * wx) * (1.0f - wy)
                               + (p1[r].x * (1.0f - wx) + p1[r].y * wx) * wy;
            __builtin_nontemporal_store(ALPHA * warped + (1.0f - ALPHA) * cu[r],
                                        &oc[pixv[r]]);
        }
    }
}

extern "C" void kernel_launch(void* const* d_in, const int* in_sizes, int n_in,
                              void* d_out, int out_size, void* d_ws, size_t ws_size,
                              hipStream_t stream) {
    const float* cur  = (const float*)d_in[0];
    const float* prev = (const float*)d_in[1];
    const float* mv   = (const float*)d_in[2];
    float* out = (float*)d_out;

    TemporalEMA_73194832658797_kernel<<<NBLK, 256, 0, stream>>>(cur, prev, mv, out);
}

// Round 8
// 562.186 us; speedup vs baseline: 2.3681x; 1.3999x over previous
//
#include <hip/hip_runtime.h>
#include <hip/hip_fp16.h>

// TemporalEMA: out = ALPHA * bilinear_warp(prev, mv) + (1-ALPHA) * cur
// R8 = R7 with the compile fix (ext_vector uint4 for nontemporal builtins).
// Layout transform: kernel 1 repacks prev [B,C,H,W] f32 -> ws [B,H,W,C16] f16
// (32 B/pixel); kernel 2 gathers taps as CONTIGUOUS 64B lines: (v00|v01)
// all-16-ch = one line, (v10|v11) = one line. Kills the y-divergence line
// amplification that pinned R4 at ~714 us. f16 quant err ~3e-3 << 8.4e-2.

#define ALPHA 0.85f

constexpr int Bc = 4;
constexpr int Cc = 16;
constexpr int Hc = 1080;
constexpr int Wc = 1920;
constexpr size_t PLANE = (size_t)Hc * Wc;
constexpr size_t WS_NEED = (size_t)Bc * PLANE * Cc * sizeof(__half);  // 265 MB

constexpr int TW = 64;
constexpr int TH = 4;
constexpr int NX = Wc / TW;          // 30
constexpr int NY = Hc / TH;          // 270
constexpr int NBLK = Bc * NY * NX;   // 32400
constexpr int NXCD = 8;
constexpr int CHUNK = NBLK / NXCD;   // 4050

constexpr int BLK_PER_B = (int)(PLANE / 256);  // 8100 (exact)

typedef float f2 __attribute__((ext_vector_type(2)));
typedef unsigned int u4 __attribute__((ext_vector_type(4)));

// ---------------- kernel 1: repack prev -> [B,H,W,C] f16 ----------------
__global__ __launch_bounds__(256) void TemporalEMA_repack_kernel(
    const float* __restrict__ prev, __half* __restrict__ ws)
{
    const int b  = blockIdx.x / BLK_PER_B;
    const int wb = blockIdx.x % BLK_PER_B;
    const size_t pix = (size_t)wb * 256 + threadIdx.x;   // within plane

    const float* src = prev + (size_t)b * Cc * PLANE + pix;
    union { __half h[16]; u4 q[2]; } u;
    #pragma unroll
    for (int c = 0; c < Cc; ++c)
        u.h[c] = __float2half(src[(size_t)c * PLANE]);

    u4* dst = (u4*)(ws + ((size_t)b * PLANE + pix) * Cc);
    __builtin_nontemporal_store(u.q[0], &dst[0]);
    __builtin_nontemporal_store(u.q[1], &dst[1]);
}

// ---------------- kernel 2: gather from packed f16 + EMA blend ----------------
__global__ __launch_bounds__(256) void TemporalEMA_73194832658797_kernel(
    const float* __restrict__ cur,
    const __half* __restrict__ wsp,
    const float* __restrict__ mv,
    float* __restrict__ out)
{
    const int bid  = blockIdx.x;
    const int work = (bid % NXCD) * CHUNK + bid / NXCD;   // chunked XCD swizzle

    const int tx  = work % NX;
    const int rem = work / NX;
    const int ty  = rem % NY;
    const int b   = rem / NY;

    const int lw = threadIdx.x & 63;
    const int lh = threadIdx.x >> 6;
    const int w  = tx * TW + lw;
    const int h  = ty * TH + lh;

    const size_t pix = (size_t)h * Wc + w;

    const float mvx = __builtin_nontemporal_load(&mv[((size_t)b * 2 + 0) * PLANE + pix]);
    const float mvy = __builtin_nontemporal_load(&mv[((size_t)b * 2 + 1) * PLANE + pix]);

    const float sxk = (float)(Wc - 1) / (float)Wc;
    const float syk = (float)(Hc - 1) / (float)Hc;
    float px = fminf(fmaxf((float)w - mvx * sxk, 0.0f), (float)(Wc - 1));
    float py = fminf(fmaxf((float)h - mvy * syk, 0.0f), (float)(Hc - 1));

    const int x0 = min((int)floorf(px), Wc - 2);   // weights absorb border clamp
    const int y0 = min((int)floorf(py), Hc - 2);
    const float wx = px - (float)x0;
    const float wy = py - (float)y0;

    const float w00 = (1.0f - wx) * (1.0f - wy);
    const float w01 = wx * (1.0f - wy);
    const float w10 = (1.0f - wx) * wy;
    const float w11 = wx * wy;

    // packed taps: pixels (y0,x0),(y0,x0+1) are 64 contiguous bytes
    const size_t p00 = ((size_t)b * PLANE + (size_t)y0 * Wc + x0) * Cc;
    const u4* g0 = (const u4*)(wsp + p00);                    // v00|v01
    const u4* g1 = (const u4*)(wsp + p00 + (size_t)Wc * Cc);  // v10|v11

    u4 q[4], r[4];
    #pragma unroll
    for (int j = 0; j < 4; ++j) { q[j] = g0[j]; r[j] = g1[j]; }

    const size_t cb0 = (size_t)b * Cc * PLANE + pix;
    float cu[Cc];
    #pragma unroll
    for (int c = 0; c < Cc; ++c)
        cu[c] = __builtin_nontemporal_load(&cur[cb0 + (size_t)c * PLANE]);

    const __half* t0 = (const __half*)&q[0];   // [32]: v00 ch0..15 | v01 ch0..15
    const __half* t1 = (const __half*)&r[0];   // [32]: v10 ch0..15 | v11 ch0..15

    #pragma unroll
    for (int c = 0; c < Cc; ++c) {
        const float v00 = __half2float(t0[c]);
        const float v01 = __half2float(t0[Cc + c]);
        const float v10 = __half2float(t1[c]);
        const float v11 = __half2float(t1[Cc + c]);
        const float warped = v00 * w00 + v01 * w01 + v10 * w10 + v11 * w11;
        __builtin_nontemporal_store(ALPHA * warped + (1.0f - ALPHA) * cu[c],
                                    &out[cb0 + (size_t)c * PLANE]);
    }
}

// ---------------- fallback: R4 direct f32 gather (if ws too small) ----------------
__global__ __launch_bounds__(256) void TemporalEMA_fallback_kernel(
    const float* __restrict__ cur,
    const float* __restrict__ prev,
    const float* __restrict__ mv,
    float* __restrict__ out)
{
    const int bid  = blockIdx.x;
    const int work = (bid % NXCD) * CHUNK + bid / NXCD;
    const int tx  = work % NX;
    const int rem = work / NX;
    const int ty  = rem % NY;
    const int b   = rem / NY;
    const int lw = threadIdx.x & 63;
    const int lh = threadIdx.x >> 6;
    const int w  = tx * TW + lw;
    const int h  = ty * TH + lh;
    const size_t pix = (size_t)h * Wc + w;

    const float mvx = __builtin_nontemporal_load(&mv[((size_t)b * 2 + 0) * PLANE + pix]);
    const float mvy = __builtin_nontemporal_load(&mv[((size_t)b * 2 + 1) * PLANE + pix]);
    const float sxk = (float)(Wc - 1) / (float)Wc;
    const float syk = (float)(Hc - 1) / (float)Hc;
    float px = fminf(fmaxf((float)w - mvx * sxk, 0.0f), (float)(Wc - 1));
    float py = fminf(fmaxf((float)h - mvy * syk, 0.0f), (float)(Hc - 1));
    const int x0 = min((int)floorf(px), Wc - 2);
    const int y0 = min((int)floorf(py), Hc - 2);
    const float wx = px - (float)x0;
    const float wy = py - (float)y0;
    const float w00 = (1.0f - wx) * (1.0f - wy);
    const float w01 = wx * (1.0f - wy);
    const float w10 = (1.0f - wx) * wy;
    const float w11 = wx * wy;
    const size_t o0 = (size_t)y0 * Wc + x0;
    const size_t o1 = o0 + Wc;
    const size_t base_b = (size_t)b * Cc * PLANE;

    #pragma unroll
    for (int cg = 0; cg < Cc; cg += 4) {
        f2 p0[4], p1[4];
        float cu[4];
        #pragma unroll
        for (int j = 0; j < 4; ++j) {
            const size_t cb = base_b + (size_t)(cg + j) * PLANE;
            p0[j] = *(const f2*)(prev + cb + o0);
            p1[j] = *(const f2*)(prev + cb + o1);
            cu[j] = __builtin_nontemporal_load(&cur[cb + pix]);
        }
        #pragma unroll
        for (int j = 0; j < 4; ++j) {
            const size_t cb = base_b + (size_t)(cg + j) * PLANE;
            const float warped = p0[j].x * w00 + p0[j].y * w01
                               + p1[j].x * w10 + p1[j].y * w11;
            __builtin_nontemporal_store(ALPHA * warped + (1.0f - ALPHA) * cu[j],
                                        &out[cb + pix]);
        }
    }
}

extern "C" void kernel_launch(void* const* d_in, const int* in_sizes, int n_in,
                              void* d_out, int out_size, void* d_ws, size_t ws_size,
                              hipStream_t stream) {
    const float* cur  = (const float*)d_in[0];
    const float* prev = (const float*)d_in[1];
    const float* mv   = (const float*)d_in[2];
    float* out = (float*)d_out;

    if (ws_size >= WS_NEED) {
        __half* ws = (__half*)d_ws;
        TemporalEMA_repack_kernel<<<Bc * BLK_PER_B, 256, 0, stream>>>(prev, ws);
        TemporalEMA_73194832658797_kernel<<<NBLK, 256, 0, stream>>>(cur, ws, mv, out);
    } else {
        TemporalEMA_fallback_kernel<<<NBLK, 256, 0, stream>>>(cur, prev, mv, out);
    }
}